// Round 1
// baseline (270.525 us; speedup 1.0000x reference)
//
#include <hip/hip_runtime.h>

// MLPDecoder: scores[e] = relu((h[src]*h[dst]) @ W1 + b1) @ W2 + b2
// E=300000, D=256. bf16 MFMA path (fp32 accum), fused single main kernel.

#define E_EDGES 300000
#define DIM 256
#define MT 32           // edges per block-iteration
#define NTILES (E_EDGES / MT)   // 9375
#define GRID_MAIN 512

typedef short bf16x8 __attribute__((ext_vector_type(8)));
typedef float f32x4 __attribute__((ext_vector_type(4)));

__device__ __forceinline__ ushort f2bf(float f) {
    union { float f; unsigned u; } v; v.f = f;
    unsigned r = v.u + 0x7FFFu + ((v.u >> 16) & 1u);  // RNE
    return (ushort)(r >> 16);
}

// W1 (fp32, [K=256][N=256]) -> W1^T bf16 ([N][K]) so B-frags are 16B-contiguous
__global__ void prep_w1t(const float* __restrict__ w1, ushort* __restrict__ w1t) {
    int idx = blockIdx.x * 256 + threadIdx.x;   // 65536 threads total
    int k = idx >> 8, n = idx & 255;            // coalesced read over n
    w1t[n * 256 + k] = f2bf(w1[k * 256 + n]);
}

__global__ __launch_bounds__(256, 2)
void decoder(const float* __restrict__ h, const int* __restrict__ edges,
             const ushort* __restrict__ w1t, const float* __restrict__ b1,
             const float* __restrict__ w2, const float* __restrict__ b2p,
             float* __restrict__ out) {
    // X tile in A-fragment-friendly layout; stride 264 (+8 pad) -> 2-way LDS aliasing only
    __shared__ ushort xlds[MT][264];     // 16.5 KB
    __shared__ float part[4][MT];        // cross-wave score partials

    const int t = threadIdx.x;
    const int w = t >> 6, lane = t & 63, quad = lane >> 4, l15 = lane & 15;

    // ---- one-time: register-resident B fragments (wave w owns N cols [64w,64w+64)) ----
    // B-frag layout (16x16x32): lane holds B[k = quad*8 + j][n = lane&15], j=0..7
    bf16x8 Bf[4][8];   // [n-tile][k-step] = 128 VGPRs
#pragma unroll
    for (int nt = 0; nt < 4; ++nt) {
        int n = w * 64 + nt * 16 + l15;
#pragma unroll
        for (int ks = 0; ks < 8; ++ks) {
            int kb = ks * 32 + quad * 8;
            Bf[nt][ks] = *(const bf16x8*)(w1t + n * 256 + kb);
        }
    }
    float b1v[4], w2v[4];
#pragma unroll
    for (int nt = 0; nt < 4; ++nt) {
        int n = w * 64 + nt * 16 + l15;
        b1v[nt] = b1[n];
        w2v[nt] = w2[n];
    }
    const float b2v = b2p[0];

    const int sm  = t >> 3;          // staging row (edge within tile), 0..31
    const int skc = (t & 7) * 32;    // staging col base (32 floats = 128B contiguous/thread)

    for (int mb = blockIdx.x; mb < NTILES; mb += gridDim.x) {
        // ---- stage X = h[src] * h[dst] as bf16 into LDS ----
        {
            int2 ed = ((const int2*)edges)[mb * MT + sm];
            const float4* hs = (const float4*)(h + (size_t)ed.x * DIM + skc);
            const float4* hv = (const float4*)(h + (size_t)ed.y * DIM + skc);
            ushort tmp[32];
#pragma unroll
            for (int j = 0; j < 8; ++j) {
                float4 a = hs[j], b = hv[j];
                tmp[4 * j + 0] = f2bf(a.x * b.x);
                tmp[4 * j + 1] = f2bf(a.y * b.y);
                tmp[4 * j + 2] = f2bf(a.z * b.z);
                tmp[4 * j + 3] = f2bf(a.w * b.w);
            }
            uint4* dst = (uint4*)&xlds[sm][skc];
            const uint4* src = (const uint4*)tmp;
            dst[0] = src[0]; dst[1] = src[1]; dst[2] = src[2]; dst[3] = src[3];
        }
        __syncthreads();

        // ---- MFMA: hidden[32 x 256] partial (this wave: 64 N cols) ----
        f32x4 acc[2][4];
#pragma unroll
        for (int ms = 0; ms < 2; ++ms)
#pragma unroll
            for (int nt = 0; nt < 4; ++nt)
                acc[ms][nt] = (f32x4){0.f, 0.f, 0.f, 0.f};

#pragma unroll
        for (int ks = 0; ks < 8; ++ks) {
            int kb = ks * 32 + quad * 8;
            // A-frag: lane holds A[m = lane&15][k = quad*8 + j]
            bf16x8 a0 = *(const bf16x8*)&xlds[l15][kb];
            bf16x8 a1 = *(const bf16x8*)&xlds[16 + l15][kb];
#pragma unroll
            for (int nt = 0; nt < 4; ++nt) {
                acc[0][nt] = __builtin_amdgcn_mfma_f32_16x16x32_bf16(a0, Bf[nt][ks], acc[0][nt], 0, 0, 0);
                acc[1][nt] = __builtin_amdgcn_mfma_f32_16x16x32_bf16(a1, Bf[nt][ks], acc[1][nt], 0, 0, 0);
            }
        }

        // ---- epilogue: relu(hidden + b1) . W2, reduce over n ----
        // C/D layout: row m = ms*16 + quad*4 + r, col n = w*64 + nt*16 + l15
        float red[2][4];
#pragma unroll
        for (int ms = 0; ms < 2; ++ms)
#pragma unroll
            for (int r = 0; r < 4; ++r) {
                float s = 0.f;
#pragma unroll
                for (int nt = 0; nt < 4; ++nt) {
                    float hid = acc[ms][nt][r] + b1v[nt];
                    s += fmaxf(hid, 0.f) * w2v[nt];
                }
                red[ms][r] = s;
            }
        // butterfly over the 16 n-lanes (stays inside each quad)
#pragma unroll
        for (int mask = 1; mask <= 8; mask <<= 1) {
#pragma unroll
            for (int ms = 0; ms < 2; ++ms)
#pragma unroll
                for (int r = 0; r < 4; ++r)
                    red[ms][r] += __shfl_xor(red[ms][r], mask);
        }
        if (l15 == 0) {
#pragma unroll
            for (int ms = 0; ms < 2; ++ms)
#pragma unroll
                for (int r = 0; r < 4; ++r)
                    part[w][ms * 16 + quad * 4 + r] = red[ms][r];
        }
        __syncthreads();
        if (t < MT)
            out[mb * MT + t] = part[0][t] + part[1][t] + part[2][t] + part[3][t] + b2v;
    }
}

extern "C" void kernel_launch(void* const* d_in, const int* in_sizes, int n_in,
                              void* d_out, int out_size, void* d_ws, size_t ws_size,
                              hipStream_t stream) {
    const float* h     = (const float*)d_in[0];
    const int*   edges = (const int*)d_in[1];
    const float* W1    = (const float*)d_in[2];
    const float* b1    = (const float*)d_in[3];
    const float* W2    = (const float*)d_in[4];
    const float* b2    = (const float*)d_in[5];
    float* out = (float*)d_out;

    ushort* w1t = (ushort*)d_ws;   // 128 KB

    prep_w1t<<<256, 256, 0, stream>>>(W1, w1t);
    decoder<<<GRID_MAIN, 256, 0, stream>>>(h, edges, w1t, b1, W2, b2, out);
}

// Round 2
// 235.489 us; speedup vs baseline: 1.1488x; 1.1488x over previous
//
#include <hip/hip_runtime.h>

// MLPDecoder: scores[e] = relu((h[src]*h[dst]) @ W1 + b1) @ W2 + b2
// E=300000, D=256. bf16 MFMA, software-pipelined gather, 16 waves/CU.

#define E_EDGES 300000
#define DIM 256
#define MT 32                    // edges per block-iteration
#define NTILES (E_EDGES / MT)    // 9375
#define BLK 512                  // 8 waves; each wave owns 32 N-cols
#define GRID_MAIN 512            // 2 blocks/CU x 256 CUs

typedef short bf16x8 __attribute__((ext_vector_type(8)));
typedef float f32x4 __attribute__((ext_vector_type(4)));

__device__ __forceinline__ ushort f2bf(float f) {
    union { float f; unsigned u; } v; v.f = f;
    unsigned r = v.u + 0x7FFFu + ((v.u >> 16) & 1u);  // RNE
    return (ushort)(r >> 16);
}
__device__ __forceinline__ float bf2f(ushort s) {
    union { unsigned u; float f; } v; v.u = ((unsigned)s) << 16;
    return v.f;
}

// W1 fp32 [K=256][N=256] -> W1^T bf16 [N][K]
__global__ void prep_w1t(const float* __restrict__ w1, ushort* __restrict__ w1t) {
    int idx = blockIdx.x * 256 + threadIdx.x;
    int k = idx >> 8, n = idx & 255;
    w1t[n * 256 + k] = f2bf(w1[k * 256 + n]);
}

// h fp32 -> bf16 (25.6M elems, 8 per thread)
__global__ void prep_hbf(const float* __restrict__ h, ushort* __restrict__ hbf) {
    int i = blockIdx.x * 256 + threadIdx.x;     // 3.2M threads
    const float4* src = (const float4*)h + (size_t)i * 2;
    float4 a = src[0], b = src[1];
    union { ushort s[8]; uint4 v; } o;
    o.s[0] = f2bf(a.x); o.s[1] = f2bf(a.y); o.s[2] = f2bf(a.z); o.s[3] = f2bf(a.w);
    o.s[4] = f2bf(b.x); o.s[5] = f2bf(b.y); o.s[6] = f2bf(b.z); o.s[7] = f2bf(b.w);
    ((uint4*)hbf)[i] = o.v;
}

template <bool BF16H>
__global__ __launch_bounds__(BLK, 4)
void decoder(const void* __restrict__ hsrc, const int2* __restrict__ edges,
             const ushort* __restrict__ w1t, const float* __restrict__ b1,
             const float* __restrict__ w2, const float* __restrict__ b2p,
             float* __restrict__ out) {
    // stride 264 (dword stride 132 ≡ 4 mod 32): uniform 8-access/bank for b128 ops
    __shared__ ushort xlds[MT][264];   // 16.9 KB
    __shared__ float part[8][MT];      // per-wave score partials

    const int t = threadIdx.x;
    const int w = t >> 6, lane = t & 63, quad = lane >> 4, l15 = lane & 15;

    // ---- register-resident W1 fragments: wave w owns N cols [32w, 32w+32) ----
    // B-frag (16x16x32): lane holds B[k = quad*8 + j][n = lane&15]
    bf16x8 Bf[2][8];   // 64 VGPRs
#pragma unroll
    for (int nt = 0; nt < 2; ++nt) {
        int n = w * 32 + nt * 16 + l15;
#pragma unroll
        for (int ks = 0; ks < 8; ++ks)
            Bf[nt][ks] = *(const bf16x8*)(w1t + n * 256 + ks * 32 + quad * 8);
    }
    float b1v[2], w2v[2];
#pragma unroll
    for (int nt = 0; nt < 2; ++nt) {
        int n = w * 32 + nt * 16 + l15;
        b1v[nt] = b1[n];
        w2v[nt] = w2[n];
    }
    const float b2v = b2p[0];

    const int sm = t >> 4;     // staging row (edge in tile) 0..31
    const int sc = t & 15;     // 16 chunks per row; 16 elems/chunk

    // prefetch registers (bf16: 32B per endpoint = 2 uint4; fp32: 64B = 4 uint4)
    uint4 gs[BF16H ? 2 : 4], gd[BF16H ? 2 : 4];

    auto issue = [&](int mb) {
        int2 ed = edges[mb * MT + sm];
        if (BF16H) {
            const uint4* ps = (const uint4*)((const ushort*)hsrc + (size_t)ed.x * DIM) + sc * 2;
            const uint4* pd = (const uint4*)((const ushort*)hsrc + (size_t)ed.y * DIM) + sc * 2;
            gs[0] = ps[0]; gs[1] = ps[1];
            gd[0] = pd[0]; gd[1] = pd[1];
        } else {
            const uint4* ps = (const uint4*)((const float*)hsrc + (size_t)ed.x * DIM) + sc * 4;
            const uint4* pd = (const uint4*)((const float*)hsrc + (size_t)ed.y * DIM) + sc * 4;
#pragma unroll
            for (int j = 0; j < 4; ++j) { gs[j] = ps[j]; gd[j] = pd[j]; }
        }
    };

    int mb = blockIdx.x;
    if (mb < NTILES) issue(mb);

    for (; mb < NTILES; mb += gridDim.x) {
        // ---- Hadamard from prefetch regs -> bf16 LDS ----
        {
            union { ushort s[16]; uint4 v[2]; } o;
            if (BF16H) {
                const ushort* s = (const ushort*)gs;
                const ushort* d = (const ushort*)gd;
#pragma unroll
                for (int j = 0; j < 16; ++j)
                    o.s[j] = f2bf(bf2f(s[j]) * bf2f(d[j]));   // bf16*bf16 exact in fp32
            } else {
                const float* s = (const float*)gs;
                const float* d = (const float*)gd;
#pragma unroll
                for (int j = 0; j < 16; ++j)
                    o.s[j] = f2bf(s[j] * d[j]);
            }
            uint4* dst = (uint4*)&xlds[sm][sc * 16];
            dst[0] = o.v[0]; dst[1] = o.v[1];
        }
        __syncthreads();

        // ---- issue next tile's gather; flies during MFMA + epilogue ----
        int mbn = mb + gridDim.x;
        if (mbn < NTILES) issue(mbn);

        // ---- MFMA: 32 edges x 32 cols per wave ----
        f32x4 acc[2][2];
#pragma unroll
        for (int ms = 0; ms < 2; ++ms)
#pragma unroll
            for (int nt = 0; nt < 2; ++nt)
                acc[ms][nt] = (f32x4){0.f, 0.f, 0.f, 0.f};

#pragma unroll
        for (int ks = 0; ks < 8; ++ks) {
            int kb = ks * 32 + quad * 8;
            bf16x8 a0 = *(const bf16x8*)&xlds[l15][kb];
            bf16x8 a1 = *(const bf16x8*)&xlds[16 + l15][kb];
#pragma unroll
            for (int nt = 0; nt < 2; ++nt) {
                acc[0][nt] = __builtin_amdgcn_mfma_f32_16x16x32_bf16(a0, Bf[nt][ks], acc[0][nt], 0, 0, 0);
                acc[1][nt] = __builtin_amdgcn_mfma_f32_16x16x32_bf16(a1, Bf[nt][ks], acc[1][nt], 0, 0, 0);
            }
        }

        // ---- epilogue: relu(hidden+b1).W2, reduce over this wave's 32 cols ----
        // C/D: row m = ms*16 + quad*4 + r, col n = w*32 + nt*16 + l15
        float red[2][4];
#pragma unroll
        for (int ms = 0; ms < 2; ++ms)
#pragma unroll
            for (int r = 0; r < 4; ++r) {
                float s = 0.f;
#pragma unroll
                for (int nt = 0; nt < 2; ++nt)
                    s += fmaxf(acc[ms][nt][r] + b1v[nt], 0.f) * w2v[nt];
                red[ms][r] = s;
            }
#pragma unroll
        for (int mask = 1; mask <= 8; mask <<= 1)
#pragma unroll
            for (int ms = 0; ms < 2; ++ms)
#pragma unroll
                for (int r = 0; r < 4; ++r)
                    red[ms][r] += __shfl_xor(red[ms][r], mask);
        if (l15 == 0)
#pragma unroll
            for (int ms = 0; ms < 2; ++ms)
#pragma unroll
                for (int r = 0; r < 4; ++r)
                    part[w][ms * 16 + quad * 4 + r] = red[ms][r];
        __syncthreads();
        if (t < MT) {
            float s = b2v;
#pragma unroll
            for (int ww = 0; ww < 8; ++ww) s += part[ww][t];
            out[mb * MT + t] = s;
        }
    }
}

extern "C" void kernel_launch(void* const* d_in, const int* in_sizes, int n_in,
                              void* d_out, int out_size, void* d_ws, size_t ws_size,
                              hipStream_t stream) {
    const float* h     = (const float*)d_in[0];
    const int2*  edges = (const int2*)d_in[1];
    const float* W1    = (const float*)d_in[2];
    const float* b1    = (const float*)d_in[3];
    const float* W2    = (const float*)d_in[4];
    const float* b2    = (const float*)d_in[5];
    float* out = (float*)d_out;

    ushort* w1t = (ushort*)d_ws;                          // 128 KB
    ushort* hbf = (ushort*)((char*)d_ws + 131072);        // 51.2 MB
    const size_t need = 131072 + (size_t)25600000 * 2;

    prep_w1t<<<256, 256, 0, stream>>>(W1, w1t);
    if (ws_size >= need) {
        prep_hbf<<<12500, 256, 0, stream>>>(h, hbf);
        decoder<true><<<GRID_MAIN, BLK, 0, stream>>>(hbf, edges, w1t, b1, W2, b2, out);
    } else {
        decoder<false><<<GRID_MAIN, BLK, 0, stream>>>(h, edges, w1t, b1, W2, b2, out);
    }
}